// Round 11
// baseline (224.072 us; speedup 1.0000x reference)
//
#include <hip/hip_runtime.h>
#include <hip/hip_bf16.h>

// Problem constants (DBRX MoE): E=8 experts, top-2, H=F=1024, T=2048 tokens.
#define T_TOK 2048
#define HID   1024
#define FF    1024
#define NE    8
#define CNT_STRIDE 64          // counts[e*CNT_STRIDE]: 256B apart -> no cacheline contention
#define RBLK 8                 // tokens per router block (256 blocks -> all CUs fed)

using short8   = __attribute__((ext_vector_type(8))) short;
using f32x4    = __attribute__((ext_vector_type(4))) float;

__device__ __forceinline__ unsigned short f32_to_bf16(float f) {
  union { float f; unsigned int u; } v; v.f = f;
  unsigned int r = v.u + 0x7fffu + ((v.u >> 16) & 1u);
  return (unsigned short)(r >> 16);
}
__device__ __forceinline__ unsigned int pack2(float a, float b) {
  return (unsigned int)f32_to_bf16(a) | ((unsigned int)f32_to_bf16(b) << 16);
}
__device__ __forceinline__ uint4 pack8(const float4 lo, const float4 hi) {
  return make_uint4(pack2(lo.x, lo.y), pack2(lo.z, lo.w),
                    pack2(hi.x, hi.y), pack2(hi.z, hi.w));
}

// async global->LDS 16B: linear LDS dest (wave-uniform base + lane*16),
// per-lane global source (may be gathered / pre-swizzled).
__device__ __forceinline__ void gload_lds16(const unsigned short* g, unsigned short* l) {
  __builtin_amdgcn_global_load_lds(
      (const __attribute__((address_space(1))) void*)g,
      (__attribute__((address_space(3))) void*)l, 16, 0, 0);
}

// ---------------------------------------------------------------- router (+ fused x->bf16)
// 256 blocks x 8 tokens; wave handles 2 tokens (lean regs: no spill, ~16
// float4 in flight/lane). fp32 logits (exact ordering for top-2), softmax
// probs as weights (DBRX: no renorm). Writes xb (bf16 x) from the regs it
// already loaded. Block-aggregated lists: ONE atomicAdd per expert per block.
__global__ __launch_bounds__(256) void router_kernel(const float* __restrict__ x,
                                                     const float* __restrict__ gw,
                                                     int* __restrict__ counts,
                                                     int* __restrict__ toks,
                                                     float* __restrict__ wts,
                                                     unsigned short* __restrict__ xb) {
  __shared__ float gws[NE * HID];      // 32 KB
  __shared__ int   s_e[RBLK * 2];
  __shared__ float s_w[RBLK * 2];
  int tid = threadIdx.x;
  int lane = tid & 63, wid = tid >> 6;
  int t0 = blockIdx.x * RBLK;

  // 1) issue gw loads (8 float4 / thread)
  float4 greg[8];
#pragma unroll
  for (int j = 0; j < 8; ++j) greg[j] = ((const float4*)gw)[j * 256 + tid];

  // 2) issue x loads (2 tokens / wave, 4 float4 each) — in flight together
  float4 xv[2][4];
#pragma unroll
  for (int tk = 0; tk < 2; ++tk) {
    const float4* xr4 = (const float4*)(x + (size_t)(t0 + wid * 2 + tk) * HID);
#pragma unroll
    for (int c = 0; c < 4; ++c) xv[tk][c] = xr4[c * 64 + lane];
  }

  // 3) stage gw to LDS
#pragma unroll
  for (int j = 0; j < 8; ++j) ((float4*)&gws[0])[j * 256 + tid] = greg[j];
  __syncthreads();

  // 4) fused x -> bf16 (reuses xv regs; coalesced ushort4 stores)
#pragma unroll
  for (int tk = 0; tk < 2; ++tk) {
    unsigned short* xrow = xb + (size_t)(t0 + wid * 2 + tk) * HID;
#pragma unroll
    for (int c = 0; c < 4; ++c) {
      ushort4 o;
      o.x = f32_to_bf16(xv[tk][c].x); o.y = f32_to_bf16(xv[tk][c].y);
      o.z = f32_to_bf16(xv[tk][c].z); o.w = f32_to_bf16(xv[tk][c].w);
      *(ushort4*)&xrow[(c * 64 + lane) * 4] = o;
    }
  }

  // 5) dot products: gw chunk shared across the wave's 2 tokens
  float acc[2][NE];
#pragma unroll
  for (int tk = 0; tk < 2; ++tk)
#pragma unroll
    for (int e = 0; e < NE; ++e) acc[tk][e] = 0.f;

#pragma unroll
  for (int c = 0; c < 4; ++c) {
#pragma unroll
    for (int e = 0; e < NE; ++e) {
      const float4 gv = *(const float4*)&gws[e * HID + (c * 64 + lane) * 4];
#pragma unroll
      for (int tk = 0; tk < 2; ++tk) {
        acc[tk][e] = fmaf(xv[tk][c].x, gv.x, acc[tk][e]);
        acc[tk][e] = fmaf(xv[tk][c].y, gv.y, acc[tk][e]);
        acc[tk][e] = fmaf(xv[tk][c].z, gv.z, acc[tk][e]);
        acc[tk][e] = fmaf(xv[tk][c].w, gv.w, acc[tk][e]);
      }
    }
  }

  // 6) wave reduce + per-token softmax/top-2
#pragma unroll
  for (int tk = 0; tk < 2; ++tk) {
#pragma unroll
    for (int off = 32; off >= 1; off >>= 1) {
#pragma unroll
      for (int e = 0; e < NE; ++e) acc[tk][e] += __shfl_xor(acc[tk][e], off);
    }
    if (lane == 0) {
      int local = wid * 2 + tk;
      float m = acc[tk][0];
#pragma unroll
      for (int e = 1; e < NE; ++e) m = fmaxf(m, acc[tk][e]);
      float p[NE], s = 0.f;
#pragma unroll
      for (int e = 0; e < NE; ++e) { p[e] = __expf(acc[tk][e] - m); s += p[e]; }
      float inv = 1.f / s;

      int e1 = 0; float b1 = p[0];
#pragma unroll
      for (int e = 1; e < NE; ++e) if (p[e] > b1) { b1 = p[e]; e1 = e; }
      int e2 = -1; float b2 = -1.f;
#pragma unroll
      for (int e = 0; e < NE; ++e) if (e != e1 && p[e] > b2) { b2 = p[e]; e2 = e; }

      s_e[local * 2]     = e1;  s_w[local * 2]     = b1 * inv;
      s_e[local * 2 + 1] = e2;  s_w[local * 2 + 1] = b2 * inv;
    }
  }
  __syncthreads();

  // 7) 8 threads, one per expert: count -> one atomicAdd -> direct global writes
  if (tid < NE) {
    int c = 0;
#pragma unroll
    for (int i = 0; i < RBLK * 2; ++i) c += (s_e[i] == tid);
    if (c > 0) {
      int base = atomicAdd(&counts[tid * CNT_STRIDE], c);
      int p = 0;
      for (int i = 0; i < RBLK * 2; ++i) {
        if (s_e[i] == tid) {
          toks[tid * T_TOK + base + p] = t0 + (i >> 1);
          wts[tid * T_TOK + base + p] = s_w[i];
          ++p;
        }
      }
    }
  }
}

// ---------------------------------------------------------------- GEMM1
// Per expert: rows = gathered tokens, computes g (= X W1^T) and v (= X V1^T)
// for one 64-col tile each, fuses hidden = silu(g)*v, writes bf16 hidden.
// Tile: BM=128, BN=64/side, BK=64. 256 threads = 4 waves, wave owns 32 rows.
// SINGLE-buffer 2-barrier loop (dbuf reverted: 64KB LDS -> 2 blk/CU regressed).
// A (gathered bf16 x) via global_load_lds, linear dest + pre-swizzled source.
// B (w1_v1) read DIRECTLY AS F32 (no separate convert pass): 8 f32 per unit ->
// in-register RNE convert -> ds_write_b128 to the same linear LDS address.
__global__ __launch_bounds__(256) void gemm1_kernel(const unsigned short* __restrict__ xb,
                                                    const float* __restrict__ w1f,
                                                    const int* __restrict__ counts,
                                                    const int* __restrict__ toks,
                                                    unsigned short* __restrict__ hidden) {
  int e = blockIdx.z;
  int cnt = counts[e * CNT_STRIDE];
  int m0 = blockIdx.y * 128;
  if (m0 >= cnt) return;
  int n0 = blockIdx.x * 64;
  const float* Wf = w1f + (size_t)e * (2 * FF * HID);

  __shared__ unsigned short sA[128 * 64];   // 16 KB
  __shared__ unsigned short sBg[64 * 64];   // 8 KB
  __shared__ unsigned short sBv[64 * 64];   // 8 KB -> 32 KB total

  int tid = threadIdx.x;
  int lane = tid & 63, wid = tid >> 6;

  const unsigned short* aptr[4]; int adst[4];
#pragma unroll
  for (int j = 0; j < 4; ++j) {
    int q = tid + 256 * j;            // 0..1023 : 128 rows x 8 units
    int row = q >> 3, u = q & 7;
    int gr = m0 + row;
    int tok = (gr < cnt) ? toks[e * T_TOK + gr] : 0;
    int su = u ^ (row & 7);           // pre-swizzled source unit
    aptr[j] = xb + (size_t)tok * HID + su * 8;
    adst[j] = q * 8;                  // linear LDS dest (elements)
  }
  const float* bgp[2]; const float* bvp[2]; int bdst[2];
#pragma unroll
  for (int j = 0; j < 2; ++j) {
    int q = tid + 256 * j;            // 0..511 : 64 rows x 8 units
    int row = q >> 3, u = q & 7;
    int su = u ^ (row & 7);
    bgp[j] = Wf + (size_t)(n0 + row) * HID + su * 8;
    bvp[j] = Wf + (size_t)(FF + n0 + row) * HID + su * 8;
    bdst[j] = q * 8;
  }

  f32x4 accg[2][4], accv[2][4];
#pragma unroll
  for (int m = 0; m < 2; ++m)
#pragma unroll
    for (int n = 0; n < 4; ++n) {
      accg[m][n] = (f32x4){0.f, 0.f, 0.f, 0.f};
      accv[m][n] = (f32x4){0.f, 0.f, 0.f, 0.f};
    }

  for (int k0 = 0; k0 < HID; k0 += 64) {
    // A: async DMA to LDS.  B: f32 load -> reg cvt -> ds_write (same layout).
#pragma unroll
    for (int j = 0; j < 4; ++j) gload_lds16(aptr[j] + k0, &sA[adst[j]]);
#pragma unroll
    for (int j = 0; j < 2; ++j) {
      float4 g0 = *(const float4*)(bgp[j] + k0);
      float4 g1 = *(const float4*)(bgp[j] + k0 + 4);
      float4 v0 = *(const float4*)(bvp[j] + k0);
      float4 v1 = *(const float4*)(bvp[j] + k0 + 4);
      *(uint4*)&sBg[bdst[j]] = pack8(g0, g1);
      *(uint4*)&sBv[bdst[j]] = pack8(v0, v1);
    }
    __syncthreads();
#pragma unroll
    for (int kk = 0; kk < 2; ++kk) {
      short8 af[2], bgf[4], bvf[4];
#pragma unroll
      for (int m = 0; m < 2; ++m) {
        int row = wid * 32 + m * 16 + (lane & 15);
        int u = (kk * 4 + (lane >> 4)) ^ (row & 7);
        af[m] = *(const short8*)&sA[row * 64 + u * 8];
      }
#pragma unroll
      for (int n = 0; n < 4; ++n) {
        int row = n * 16 + (lane & 15);
        int u = (kk * 4 + (lane >> 4)) ^ (row & 7);
        bgf[n] = *(const short8*)&sBg[row * 64 + u * 8];
        bvf[n] = *(const short8*)&sBv[row * 64 + u * 8];
      }
#pragma unroll
      for (int m = 0; m < 2; ++m)
#pragma unroll
        for (int n = 0; n < 4; ++n) {
          accg[m][n] = __builtin_amdgcn_mfma_f32_16x16x32_bf16(af[m], bgf[n], accg[m][n], 0, 0, 0);
          accv[m][n] = __builtin_amdgcn_mfma_f32_16x16x32_bf16(af[m], bvf[n], accv[m][n], 0, 0, 0);
        }
    }
    __syncthreads();
  }

  // epilogue: hidden = silu(g) * v, bf16 store. C/D layout: col=lane&15, row=(lane>>4)*4+j
  unsigned short* Hseg = hidden + (size_t)e * T_TOK * FF;
#pragma unroll
  for (int m = 0; m < 2; ++m) {
#pragma unroll
    for (int j = 0; j < 4; ++j) {
      int row = wid * 32 + m * 16 + (lane >> 4) * 4 + j;
      int gr = m0 + row;
      if (gr < cnt) {
#pragma unroll
        for (int n = 0; n < 4; ++n) {
          int col = n0 + n * 16 + (lane & 15);
          float g = accg[m][n][j];
          float v = accv[m][n][j];
          float val = (g / (1.f + __expf(-g))) * v;
          Hseg[(size_t)gr * FF + col] = f32_to_bf16(val);
        }
      }
    }
  }
}

// ---------------------------------------------------------------- GEMM2
// out[tok,:] += wt * (hidden_row @ w2_e^T). Single-buffer; B = w2 f32 direct.
__global__ __launch_bounds__(256) void gemm2_kernel(const unsigned short* __restrict__ hidden,
                                                    const float* __restrict__ w2f,
                                                    const int* __restrict__ counts,
                                                    const int* __restrict__ toks,
                                                    const float* __restrict__ wts,
                                                    float* __restrict__ out) {
  int e = blockIdx.z;
  int cnt = counts[e * CNT_STRIDE];
  int m0 = blockIdx.y * 128;
  if (m0 >= cnt) return;
  int n0 = blockIdx.x * 64;
  const unsigned short* A = hidden + (size_t)e * T_TOK * FF;
  const float* Wf = w2f + (size_t)e * HID * FF;

  __shared__ unsigned short sA[128 * 64];   // 16 KB
  __shared__ unsigned short sB[64 * 64];    // 8 KB -> 24 KB total

  int tid = threadIdx.x;
  int lane = tid & 63, wid = tid >> 6;

  const unsigned short* aptr[4]; int adst[4];
#pragma unroll
  for (int j = 0; j < 4; ++j) {
    int q = tid + 256 * j;
    int row = q >> 3, u = q & 7;
    int su = u ^ (row & 7);
    aptr[j] = A + (size_t)(m0 + row) * FF + su * 8;   // padded rows read stale: masked at write
    adst[j] = q * 8;
  }
  const float* bp[2]; int bdst[2];
#pragma unroll
  for (int j = 0; j < 2; ++j) {
    int q = tid + 256 * j;
    int row = q >> 3, u = q & 7;
    int su = u ^ (row & 7);
    bp[j] = Wf + (size_t)(n0 + row) * FF + su * 8;
    bdst[j] = q * 8;
  }

  f32x4 acc[2][4];
#pragma unroll
  for (int m = 0; m < 2; ++m)
#pragma unroll
    for (int n = 0; n < 4; ++n) acc[m][n] = (f32x4){0.f, 0.f, 0.f, 0.f};

  for (int k0 = 0; k0 < FF; k0 += 64) {
#pragma unroll
    for (int j = 0; j < 4; ++j) gload_lds16(aptr[j] + k0, &sA[adst[j]]);
#pragma unroll
    for (int j = 0; j < 2; ++j) {
      float4 b0 = *(const float4*)(bp[j] + k0);
      float4 b1 = *(const float4*)(bp[j] + k0 + 4);
      *(uint4*)&sB[bdst[j]] = pack8(b0, b1);
    }
    __syncthreads();
#pragma unroll
    for (int kk = 0; kk < 2; ++kk) {
      short8 af[2], bf[4];
#pragma unroll
      for (int m = 0; m < 2; ++m) {
        int row = wid * 32 + m * 16 + (lane & 15);
        int u = (kk * 4 + (lane >> 4)) ^ (row & 7);
        af[m] = *(const short8*)&sA[row * 64 + u * 8];
      }
#pragma unroll
      for (int n = 0; n < 4; ++n) {
        int row = n * 16 + (lane & 15);
        int u = (kk * 4 + (lane >> 4)) ^ (row & 7);
        bf[n] = *(const short8*)&sB[row * 64 + u * 8];
      }
#pragma unroll
      for (int m = 0; m < 2; ++m)
#pragma unroll
        for (int n = 0; n < 4; ++n)
          acc[m][n] = __builtin_amdgcn_mfma_f32_16x16x32_bf16(af[m], bf[n], acc[m][n], 0, 0, 0);
    }
    __syncthreads();
  }

  // epilogue: weighted atomic scatter into out (each out element hit by exactly K=2 experts)
#pragma unroll
  for (int m = 0; m < 2; ++m) {
#pragma unroll
    for (int j = 0; j < 4; ++j) {
      int row = wid * 32 + m * 16 + (lane >> 4) * 4 + j;
      int gr = m0 + row;
      if (gr < cnt) {
        int tok = toks[e * T_TOK + gr];
        float wt = wts[e * T_TOK + gr];
#pragma unroll
        for (int n = 0; n < 4; ++n) {
          int col = n0 + n * 16 + (lane & 15);
          atomicAdd(&out[(size_t)tok * HID + col], acc[m][n][j] * wt);
        }
      }
    }
  }
}

// ---------------------------------------------------------------- launch
extern "C" void kernel_launch(void* const* d_in, const int* in_sizes, int n_in,
                              void* d_out, int out_size, void* d_ws, size_t ws_size,
                              hipStream_t stream) {
  const float* x  = (const float*)d_in[0];
  const float* gw = (const float*)d_in[1];
  const float* w1 = (const float*)d_in[2];
  const float* w2 = (const float*)d_in[3];
  float* out = (float*)d_out;

  // workspace layout (bytes):
  //   0      : counts[8 * CNT_STRIDE] int  (2 KB, 4 KB reserved)
  //   4096   : toks[8*2048] int            (64 KB)
  //   69632  : wts[8*2048] float           (64 KB)
  //   135168 : xb   bf16 x                 (4 MB)
  //   +      : hidden bf16 [8*2048][1024]  (32 MB)   total ~36 MB
  char* ws = (char*)d_ws;
  int*   counts = (int*)ws;
  int*   toks   = (int*)(ws + 4096);
  float* wts    = (float*)(ws + 4096 + 65536);
  unsigned short* xb  = (unsigned short*)(ws + 135168);
  unsigned short* hid = xb + (size_t)T_TOK * HID;

  hipMemsetAsync(counts, 0, 4096, stream);
  hipMemsetAsync(d_out, 0, (size_t)out_size * sizeof(float), stream);

  router_kernel<<<T_TOK / RBLK, 256, 0, stream>>>(x, gw, counts, toks, wts, xb);

  gemm1_kernel<<<dim3(FF / 64, T_TOK / 128, NE), 256, 0, stream>>>(xb, w1, counts, toks, hid);
  gemm2_kernel<<<dim3(HID / 64, T_TOK / 128, NE), 256, 0, stream>>>(hid, w2, counts, toks, wts, out);
}